// Round 6
// baseline (930.340 us; speedup 1.0000x reference)
//
#include <hip/hip_runtime.h>
#include <math.h>

constexpr int N_NODES = 500000;
constexpr int N_EDGES = 8000000;
constexpr int IN_DIM = 10, HID_DIM = 35, OUT_DIM = 2;

constexpr int BUCKET_BITS = 11;                       // 2048 dst-nodes per bucket
constexpr int BNODES = 1 << BUCKET_BITS;              // 2048
constexpr int NB = (N_NODES + BNODES - 1) / BNODES;   // 245 buckets

constexpr int CHUNK_BITS = 16;                        // 65536 src-nodes per chunk (2.6 MB of x)
constexpr int NCHUNK = 8;                             // ceil(500000 / 65536)
constexpr int NBINS = NB * NCHUNK;                    // 1960 (bucket,chunk) bins
constexpr int NBINP = 2048;                           // padded for scan

constexpr int PART_TPB = 1024;
constexpr int EPT = 16;
constexpr int TILE = PART_TPB * EPT;                  // 16384
constexpr int NTILES = (N_EDGES + TILE - 1) / TILE;   // 489

__device__ __forceinline__ void atomAddF(float* p, float v) { unsafeAtomicAdd(p, v); }

__device__ __forceinline__ int bin_of(int d, int s) {
    return ((d >> BUCKET_BITS) << 3) | (s >> CHUNK_BITS);
}

// ---------------- zero bin counters ----------------
__global__ void zero_small_kernel(unsigned* __restrict__ bcount) {
    int i = blockIdx.x * blockDim.x + threadIdx.x;
    if (i < NBINP) bcount[i] = 0u;
}

// ---------------- histogram over (dst-bucket, src-chunk) bins ----------------
__global__ void hist_kernel(const int* __restrict__ src, const int* __restrict__ dst,
                            unsigned* __restrict__ bcount, int E) {
    __shared__ unsigned h[NBINP];
    for (int k = threadIdx.x; k < NBINP; k += blockDim.x) h[k] = 0u;
    __syncthreads();
    int stride = gridDim.x * blockDim.x;
    for (int e = blockIdx.x * blockDim.x + threadIdx.x; e < E; e += stride)
        atomicAdd(&h[bin_of(dst[e], src[e])], 1u);
    __syncthreads();
    for (int k = threadIdx.x; k < NBINS; k += blockDim.x)
        if (h[k]) atomicAdd(&bcount[k], h[k]);
}

// ---------------- exclusive scan of 2048 bin counts (1 block, 2/thread) -------
__global__ void scan_kernel(const unsigned* __restrict__ bcount,
                            unsigned* __restrict__ bbase, unsigned* __restrict__ bcursor) {
    __shared__ unsigned s[1024];
    int t = threadIdx.x;
    unsigned a0 = bcount[2 * t], a1 = bcount[2 * t + 1];
    unsigned tsum = a0 + a1;
    s[t] = tsum; __syncthreads();
    for (int off = 1; off < 1024; off <<= 1) {
        unsigned a = (t >= off) ? s[t - off] : 0u;
        __syncthreads();
        s[t] += a;
        __syncthreads();
    }
    unsigned pre = s[t] - tsum;  // exclusive prefix of pair
    bbase[2 * t] = pre;          bcursor[2 * t] = pre;
    bbase[2 * t + 1] = pre + a0; bcursor[2 * t + 1] = pre + a0;
    if (t == 0) bbase[NBINP] = (unsigned)N_EDGES;
}

// ---------------- partition: pack (src<<11 | dst&2047) grouped by bin ----------
__global__ __launch_bounds__(PART_TPB) void partition_kernel(
        const int* __restrict__ src, const int* __restrict__ dst,
        unsigned* __restrict__ bcursor, unsigned* __restrict__ packed, int E) {
    __shared__ unsigned h[NBINP], base[NBINP], c2[NBINP];  // 24 KB
    int t = threadIdx.x;
    for (int k = t; k < NBINP; k += PART_TPB) { h[k] = 0u; c2[k] = 0u; }
    __syncthreads();
    int tile0 = blockIdx.x * TILE;
    int d[EPT], sv[EPT];
    #pragma unroll
    for (int q = 0; q < EPT; ++q) {
        int e = tile0 + q * PART_TPB + t;
        d[q] = (e < E) ? dst[e] : -1;
        sv[q] = (e < E) ? src[e] : 0;
        if (d[q] >= 0) atomicAdd(&h[bin_of(d[q], sv[q])], 1u);
    }
    __syncthreads();
    for (int k = t; k < NBINS; k += PART_TPB)
        if (h[k]) base[k] = atomicAdd(&bcursor[k], h[k]);
    __syncthreads();
    #pragma unroll
    for (int q = 0; q < EPT; ++q) {
        if (d[q] >= 0) {
            int b = bin_of(d[q], sv[q]);
            unsigned pos = base[b] + atomicAdd(&c2[b], 1u);
            packed[pos] = ((unsigned)sv[q] << BUCKET_BITS) | (unsigned)(d[q] & (BNODES - 1));
        }
    }
}

// ---------------- per-bucket: degree -> dinv, prescale x in place --------------
__global__ __launch_bounds__(1024) void deg_kernel(
        const unsigned* __restrict__ packed, const unsigned* __restrict__ bbase,
        float* __restrict__ dinv, float* __restrict__ x, int N) {
    __shared__ unsigned cnt[BNODES];
    int b = blockIdx.x, t = threadIdx.x;
    for (int k = t; k < BNODES; k += 1024) cnt[k] = 0u;
    __syncthreads();
    unsigned beg = bbase[b * NCHUNK], end = bbase[b * NCHUNK + NCHUNK];
    for (unsigned e = beg + t; e < end; e += 1024)
        atomicAdd(&cnt[packed[e] & (BNODES - 1)], 1u);
    __syncthreads();
    int node0 = b << BUCKET_BITS;
    for (int k = t; k < BNODES; k += 1024) {
        int i = node0 + k;
        if (i >= N) continue;
        float di = rsqrtf((float)cnt[k] + 1.0f);  // +1 = self-loop
        dinv[i] = di;
        float2* xr = reinterpret_cast<float2*>(x + (size_t)i * IN_DIM);
        #pragma unroll
        for (int q = 0; q < 5; ++q) { float2 v = xr[q]; v.x *= di; v.y *= di; xr[q] = v; }
    }
}

// ---------------- per-bucket layer-1: LDS-accumulate + fused MLP ---------------
// Edges arrive grouped by src-chunk (2.6 MB x-slices) -> gathers are L2-resident.
__global__ __launch_bounds__(1024) void agg1_kernel(
        const unsigned* __restrict__ packed, const unsigned* __restrict__ bbase,
        const float* __restrict__ xs, const float* __restrict__ dinv,
        const float* __restrict__ W1, const float* __restrict__ b1,
        const float* __restrict__ W2, float2* __restrict__ ts, int N) {
    __shared__ float acc[BNODES * IN_DIM];  // 80 KB
    __shared__ float sW1[IN_DIM * HID_DIM];
    __shared__ float sb1[HID_DIM];
    __shared__ float sW2[HID_DIM * OUT_DIM];
    int b = blockIdx.x, t = threadIdx.x;
    for (int k = t; k < BNODES * IN_DIM; k += 1024) acc[k] = 0.0f;
    for (int k = t; k < IN_DIM * HID_DIM; k += 1024) sW1[k] = W1[k];
    if (t < HID_DIM) sb1[t] = b1[t];
    if (t < HID_DIM * OUT_DIM) sW2[t] = W2[t];
    __syncthreads();
    unsigned beg = bbase[b * NCHUNK], end = bbase[b * NCHUNK + NCHUNK];
    unsigned e = beg + t;
    unsigned p = (e < end) ? packed[e] : 0u;
    while (e < end) {
        unsigned en = e + 1024;
        unsigned pn = (en < end) ? packed[en] : 0u;  // read-ahead: break dep chain
        const float2* xr = reinterpret_cast<const float2*>(xs + (size_t)(p >> BUCKET_BITS) * IN_DIM);
        float* a = acc + (p & (BNODES - 1)) * IN_DIM;
        #pragma unroll
        for (int q = 0; q < 5; ++q) {
            float2 v = xr[q];
            atomAddF(a + 2 * q + 0, v.x);
            atomAddF(a + 2 * q + 1, v.y);
        }
        p = pn; e = en;
    }
    __syncthreads();
    int node0 = b << BUCKET_BITS;
    for (int k = t; k < BNODES; k += 1024) {
        int i = node0 + k;
        if (i >= N) continue;
        float di = dinv[i];
        const float2* xi = reinterpret_cast<const float2*>(xs + (size_t)i * IN_DIM);
        float v[IN_DIM];
        #pragma unroll
        for (int q = 0; q < 5; ++q) {
            float2 xv = xi[q];
            v[2*q+0] = di * (acc[k * IN_DIM + 2*q+0] + xv.x);
            v[2*q+1] = di * (acc[k * IN_DIM + 2*q+1] + xv.y);
        }
        float t0 = 0.0f, t1 = 0.0f;
        #pragma unroll
        for (int j = 0; j < HID_DIM; ++j) {
            float hh = sb1[j];
            #pragma unroll
            for (int q = 0; q < IN_DIM; ++q) hh = fmaf(v[q], sW1[q * HID_DIM + j], hh);
            hh = fmaxf(hh, 0.0f);
            t0 = fmaf(hh, sW2[2*j+0], t0);
            t1 = fmaf(hh, sW2[2*j+1], t1);
        }
        ts[i] = make_float2(t0 * di, t1 * di);
    }
}

// ---------------- per-bucket layer-2: LDS-accumulate + log_softmax -------------
__global__ __launch_bounds__(1024) void agg2_kernel(
        const unsigned* __restrict__ packed, const unsigned* __restrict__ bbase,
        const float2* __restrict__ ts, const float* __restrict__ dinv,
        const float* __restrict__ b2, float2* __restrict__ out, int N) {
    __shared__ float acc[BNODES * 2];  // 16 KB
    int b = blockIdx.x, t = threadIdx.x;
    for (int k = t; k < BNODES * 2; k += 1024) acc[k] = 0.0f;
    __syncthreads();
    unsigned beg = bbase[b * NCHUNK], end = bbase[b * NCHUNK + NCHUNK];
    for (unsigned e = beg + t; e < end; e += 1024) {
        unsigned p = packed[e];
        float2 tv = ts[p >> BUCKET_BITS];
        unsigned dl = p & (BNODES - 1);
        atomAddF(&acc[dl * 2 + 0], tv.x);
        atomAddF(&acc[dl * 2 + 1], tv.y);
    }
    __syncthreads();
    float b20 = b2[0], b21 = b2[1];
    int node0 = b << BUCKET_BITS;
    for (int k = t; k < BNODES; k += 1024) {
        int i = node0 + k;
        if (i >= N) continue;
        float di = dinv[i];
        float2 tv = ts[i];  // self-loop (already has dinv[i] factor)
        float a0 = di * (acc[k*2+0] + tv.x) + b20;
        float a1 = di * (acc[k*2+1] + tv.y) + b21;
        float m = fmaxf(a0, a1);
        float lse = m + logf(expf(a0 - m) + expf(a1 - m));
        out[i] = make_float2(a0 - lse, a1 - lse);
    }
}

extern "C" void kernel_launch(void* const* d_in, const int* in_sizes, int n_in,
                              void* d_out, int out_size, void* d_ws, size_t ws_size,
                              hipStream_t stream) {
    float* x        = (float*)d_in[0];       // prescaled in place (harness restores)
    const int* ei   = (const int*)d_in[1];   // [2, E]: src row then dst row
    const float* W1 = (const float*)d_in[2];
    const float* b1 = (const float*)d_in[3];
    const float* W2 = (const float*)d_in[4];
    const float* b2 = (const float*)d_in[5];
    float2* out = (float2*)d_out;

    const int* src = ei;
    const int* dst = ei + N_EDGES;

    // workspace (4B elems):
    // bcount[2048] | bbase[2049] | bcursor[2048] | dinv[N] | ts[2N] | packed[E] ~= 38 MB
    unsigned* bcount  = (unsigned*)d_ws;
    unsigned* bbase   = bcount + NBINP;
    unsigned* bcursor = bbase + NBINP + 1;
    float*    dinv    = (float*)(bcursor + NBINP);
    float2*   ts      = (float2*)(dinv + N_NODES);
    unsigned* packed  = (unsigned*)(ts + N_NODES);

    zero_small_kernel<<<2, 1024, 0, stream>>>(bcount);
    hist_kernel<<<1024, 256, 0, stream>>>(src, dst, bcount, N_EDGES);
    scan_kernel<<<1, 1024, 0, stream>>>(bcount, bbase, bcursor);
    partition_kernel<<<NTILES, PART_TPB, 0, stream>>>(src, dst, bcursor, packed, N_EDGES);
    deg_kernel<<<NB, 1024, 0, stream>>>(packed, bbase, dinv, x, N_NODES);
    agg1_kernel<<<NB, 1024, 0, stream>>>(packed, bbase, x, dinv, W1, b1, W2, ts, N_NODES);
    agg2_kernel<<<NB, 1024, 0, stream>>>(packed, bbase, ts, dinv, b2, out, N_NODES);
}

// Round 7
// 650.868 us; speedup vs baseline: 1.4294x; 1.4294x over previous
//
#include <hip/hip_runtime.h>
#include <math.h>

constexpr int N_NODES = 500000;
constexpr int N_EDGES = 8000000;
constexpr int IN_DIM = 10, HID_DIM = 35, OUT_DIM = 2;

constexpr int BUCKET_BITS = 11;                       // 2048 dst-nodes per bucket
constexpr int BNODES = 1 << BUCKET_BITS;              // 2048
constexpr int NB = (N_NODES + BNODES - 1) / BNODES;   // 245 buckets
constexpr int NBP = 256;                              // padded

constexpr int PART_TPB = 1024;
constexpr int EPT = 16;
constexpr int TILE = PART_TPB * EPT;                  // 16384
constexpr int NTILES = (N_EDGES + TILE - 1) / TILE;   // 489

// ---------------- zero bucket counters ----------------
__global__ void zero_small_kernel(unsigned* __restrict__ bcount) {
    bcount[threadIdx.x] = 0u;
}

// ---------------- histogram: edges per dst-bucket (245 bins) ----------------
__global__ void hist_kernel(const int* __restrict__ dst, unsigned* __restrict__ bcount, int E) {
    __shared__ unsigned h[NBP];
    h[threadIdx.x] = 0u;
    __syncthreads();
    int stride = gridDim.x * blockDim.x;
    for (int e = blockIdx.x * blockDim.x + threadIdx.x; e < E; e += stride)
        atomicAdd(&h[dst[e] >> BUCKET_BITS], 1u);
    __syncthreads();
    if (h[threadIdx.x]) atomicAdd(&bcount[threadIdx.x], h[threadIdx.x]);
}

// ---------------- exclusive scan of bucket counts (1 block, 256) -------------
__global__ void scan_kernel(const unsigned* __restrict__ bcount,
                            unsigned* __restrict__ bbase, unsigned* __restrict__ bcursor,
                            unsigned* __restrict__ rowstart) {
    __shared__ unsigned s[NBP];
    int t = threadIdx.x;
    unsigned v = bcount[t];
    s[t] = v; __syncthreads();
    for (int off = 1; off < NBP; off <<= 1) {
        unsigned a = (t >= off) ? s[t - off] : 0u;
        __syncthreads();
        s[t] += a;
        __syncthreads();
    }
    bbase[t] = s[t] - v;  bcursor[t] = s[t] - v;   // bins >= NB are zero => bbase[NB] = E
    if (t == 0) { bbase[NBP] = (unsigned)N_EDGES; rowstart[N_NODES] = (unsigned)N_EDGES; }
}

// ---------------- partition: pack (src<<11 | dst&2047) grouped by bucket ------
__global__ __launch_bounds__(PART_TPB) void partition_kernel(
        const int* __restrict__ src, const int* __restrict__ dst,
        unsigned* __restrict__ bcursor, unsigned* __restrict__ packed, int E) {
    __shared__ unsigned h[NBP], base[NBP], c2[NBP];
    int t = threadIdx.x;
    for (int k = t; k < NBP; k += PART_TPB) { h[k] = 0u; c2[k] = 0u; }
    __syncthreads();
    int tile0 = blockIdx.x * TILE;
    int d[EPT];
    #pragma unroll
    for (int q = 0; q < EPT; ++q) {
        int e = tile0 + q * PART_TPB + t;
        d[q] = (e < E) ? dst[e] : -1;
        if (d[q] >= 0) atomicAdd(&h[d[q] >> BUCKET_BITS], 1u);
    }
    __syncthreads();
    for (int k = t; k < NBP; k += PART_TPB)
        if (h[k]) base[k] = atomicAdd(&bcursor[k], h[k]);
    __syncthreads();
    #pragma unroll
    for (int q = 0; q < EPT; ++q) {
        int e = tile0 + q * PART_TPB + t;
        if (d[q] >= 0) {
            int b = d[q] >> BUCKET_BITS;
            unsigned pos = base[b] + atomicAdd(&c2[b], 1u);
            packed[pos] = ((unsigned)src[e] << BUCKET_BITS) | (unsigned)(d[q] & (BNODES - 1));
        }
    }
}

// ---------------- per-bucket CSR build + dinv + x-prescale --------------------
// LDS hist of local dst -> LDS scan -> LDS-cursor scatter of src into the
// bucket's contiguous csr window (131 KB => writes combine in L2).
__global__ __launch_bounds__(1024) void csrbuild_kernel(
        const unsigned* __restrict__ packed, const unsigned* __restrict__ bbase,
        unsigned* __restrict__ rowstart, int* __restrict__ csr,
        float* __restrict__ dinv, float* __restrict__ x, int N) {
    __shared__ unsigned cnt[BNODES];   // degrees (kept intact)
    __shared__ unsigned pref[BNODES];  // exclusive prefix -> then reused as cursor
    __shared__ unsigned stmp[1024];
    int b = blockIdx.x, t = threadIdx.x;
    cnt[t] = 0u; cnt[t + 1024] = 0u;
    __syncthreads();
    unsigned base = bbase[b], end = bbase[b + 1];
    for (unsigned e = base + t; e < end; e += 1024)
        atomicAdd(&cnt[packed[e] & (BNODES - 1)], 1u);
    __syncthreads();
    // scan 2048 counts, 2 per thread
    unsigned a0 = cnt[2 * t], a1 = cnt[2 * t + 1];
    unsigned tsum = a0 + a1;
    stmp[t] = tsum; __syncthreads();
    for (int off = 1; off < 1024; off <<= 1) {
        unsigned a = (t >= off) ? stmp[t - off] : 0u;
        __syncthreads();
        stmp[t] += a;
        __syncthreads();
    }
    unsigned pre = stmp[t] - tsum;
    pref[2 * t] = pre; pref[2 * t + 1] = pre + a0;
    __syncthreads();
    // rowstart + dinv + prescale (reads cnt/pref before pref is consumed)
    int node0 = b << BUCKET_BITS;
    for (int k = t; k < BNODES; k += 1024) {
        int i = node0 + k;
        if (i < N) {
            rowstart[i] = base + pref[k];
            float di = rsqrtf((float)cnt[k] + 1.0f);  // +1 = self-loop
            dinv[i] = di;
            float2* xr = reinterpret_cast<float2*>(x + (size_t)i * IN_DIM);
            #pragma unroll
            for (int q = 0; q < 5; ++q) { float2 v = xr[q]; v.x *= di; v.y *= di; xr[q] = v; }
        }
    }
    __syncthreads();
    // scatter src into csr, grouped by local dst (pref doubles as cursor)
    for (unsigned e = base + t; e < end; e += 1024) {
        unsigned p = packed[e];
        unsigned dl = p & (BNODES - 1);
        unsigned pos = base + atomicAdd(&pref[dl], 1u);
        csr[pos] = (int)(p >> BUCKET_BITS);
    }
}

// ---------------- layer-1: register-accumulating gather + fused MLP -----------
__global__ __launch_bounds__(256) void gather1_kernel(
        const int* __restrict__ csr, const unsigned* __restrict__ rowstart,
        const float* __restrict__ xs, const float* __restrict__ dinv,
        const float* __restrict__ W1, const float* __restrict__ b1,
        const float* __restrict__ W2, float2* __restrict__ ts, int N) {
    __shared__ float sW1[IN_DIM * HID_DIM];
    __shared__ float sb1[HID_DIM];
    __shared__ float sW2[HID_DIM * OUT_DIM];
    for (int k = threadIdx.x; k < IN_DIM * HID_DIM; k += 256) sW1[k] = W1[k];
    if (threadIdx.x < HID_DIM) sb1[threadIdx.x] = b1[threadIdx.x];
    if (threadIdx.x < HID_DIM * OUT_DIM) sW2[threadIdx.x] = W2[threadIdx.x];
    __syncthreads();

    int i = blockIdx.x * 256 + threadIdx.x;
    if (i >= N) return;
    unsigned beg = rowstart[i], end = rowstart[i + 1];
    float v[IN_DIM];
    const float2* xi = reinterpret_cast<const float2*>(xs + (size_t)i * IN_DIM);
    #pragma unroll
    for (int q = 0; q < 5; ++q) { float2 u = xi[q]; v[2*q] = u.x; v[2*q+1] = u.y; }
    unsigned e = beg;
    int s = (e < end) ? csr[e] : 0;
    while (e < end) {
        int sn = (e + 1 < end) ? csr[e + 1] : 0;  // read-ahead: break dep chain
        const float2* xr = reinterpret_cast<const float2*>(xs + (size_t)s * IN_DIM);
        #pragma unroll
        for (int q = 0; q < 5; ++q) { float2 u = xr[q]; v[2*q] += u.x; v[2*q+1] += u.y; }
        s = sn; ++e;
    }
    float di = dinv[i];
    #pragma unroll
    for (int k = 0; k < IN_DIM; ++k) v[k] *= di;
    float t0 = 0.0f, t1 = 0.0f;
    #pragma unroll
    for (int j = 0; j < HID_DIM; ++j) {
        float hh = sb1[j];
        #pragma unroll
        for (int q = 0; q < IN_DIM; ++q) hh = fmaf(v[q], sW1[q * HID_DIM + j], hh);
        hh = fmaxf(hh, 0.0f);
        t0 = fmaf(hh, sW2[2*j+0], t0);
        t1 = fmaf(hh, sW2[2*j+1], t1);
    }
    ts[i] = make_float2(t0 * di, t1 * di);
}

// ---------------- layer-2: register gather + bias + log_softmax ---------------
__global__ __launch_bounds__(256) void gather2_kernel(
        const int* __restrict__ csr, const unsigned* __restrict__ rowstart,
        const float2* __restrict__ ts, const float* __restrict__ dinv,
        const float* __restrict__ b2, float2* __restrict__ out, int N) {
    int i = blockIdx.x * 256 + threadIdx.x;
    if (i >= N) return;
    unsigned beg = rowstart[i], end = rowstart[i + 1];
    float2 acc = ts[i];  // self-loop (already carries dinv[i] factor)
    unsigned e = beg;
    int s = (e < end) ? csr[e] : 0;
    while (e < end) {
        int sn = (e + 1 < end) ? csr[e + 1] : 0;
        float2 tv = ts[s];
        acc.x += tv.x; acc.y += tv.y;
        s = sn; ++e;
    }
    float di = dinv[i];
    float a0 = di * acc.x + b2[0];
    float a1 = di * acc.y + b2[1];
    float m = fmaxf(a0, a1);
    float lse = m + logf(expf(a0 - m) + expf(a1 - m));
    out[i] = make_float2(a0 - lse, a1 - lse);
}

extern "C" void kernel_launch(void* const* d_in, const int* in_sizes, int n_in,
                              void* d_out, int out_size, void* d_ws, size_t ws_size,
                              hipStream_t stream) {
    float* x        = (float*)d_in[0];       // prescaled in place (harness restores)
    const int* ei   = (const int*)d_in[1];   // [2, E]: src row then dst row
    const float* W1 = (const float*)d_in[2];
    const float* b1 = (const float*)d_in[3];
    const float* W2 = (const float*)d_in[4];
    const float* b2 = (const float*)d_in[5];
    float2* out = (float2*)d_out;

    const int* src = ei;
    const int* dst = ei + N_EDGES;

    // workspace (4B elems):
    // bcount[256] | bbase[257] | bcursor[256] | rowstart[N+1] | dinv[N] | ts[2N]
    // | packed[E] | csr[E]      ~= 72 MB
    unsigned* bcount   = (unsigned*)d_ws;
    unsigned* bbase    = bcount + NBP;
    unsigned* bcursor  = bbase + NBP + 1;
    unsigned* rowstart = bcursor + NBP;
    float*    dinv     = (float*)(rowstart + N_NODES + 1);
    float2*   ts       = (float2*)(dinv + N_NODES);
    unsigned* packed   = (unsigned*)(ts + N_NODES);
    int*      csr      = (int*)(packed + N_EDGES);

    const int node_grid = (N_NODES + 255) / 256;  // 1954

    zero_small_kernel<<<1, NBP, 0, stream>>>(bcount);
    hist_kernel<<<1024, NBP, 0, stream>>>(dst, bcount, N_EDGES);
    scan_kernel<<<1, NBP, 0, stream>>>(bcount, bbase, bcursor, rowstart);
    partition_kernel<<<NTILES, PART_TPB, 0, stream>>>(src, dst, bcursor, packed, N_EDGES);
    csrbuild_kernel<<<NB, 1024, 0, stream>>>(packed, bbase, rowstart, csr, dinv, x, N_NODES);
    gather1_kernel<<<node_grid, 256, 0, stream>>>(csr, rowstart, x, dinv, W1, b1, W2, ts, N_NODES);
    gather2_kernel<<<node_grid, 256, 0, stream>>>(csr, rowstart, ts, dinv, b2, out, N_NODES);
}